// Round 1
// baseline (296.985 us; speedup 1.0000x reference)
//
#include <hip/hip_runtime.h>
#include <hip/hip_bf16.h>

// Problem constants (fixed by the reference):
//   B=8192 rows, N=4096 omegas/row, W=1000 bins, L=101 Legendre terms.
// Key simplifications (exact, not approximations):
//   * normalization of pdf cancels in grad/pdf -> skip it
//   * gauss branch of _pdf_no_cosine is never selected when the output uses
//     the pdf (needs sigma>0.6>0.2) -> skip it
//   * sigma<=0.6 rows are pure elementwise -omega/sigma^2

#define L_TERMS 101
#define W_BINS 1000
#define N_COLS 4096
#define ROWS_PER_BLK 8
#define TPB 256
#define TRANS_STRIDE 1024  // padded so OOB lanes (w in [1000,1024)) stay in-bounds

// ---------------------------------------------------------------------------
// Kernel 1: transpose sine_terms [1000][101] -> sine_t [101][1024] (padded)
// so the series GEMM reads it with lane-coalesced float4 loads.
__global__ __launch_bounds__(128) void transpose_sine(
    const float* __restrict__ sine, float* __restrict__ sine_t) {
  int w = blockIdx.x;   // 0..999
  int t = threadIdx.x;  // 0..127
  if (t < L_TERMS) sine_t[(size_t)t * TRANS_STRIDE + w] = sine[(size_t)w * L_TERMS + t];
}

// ---------------------------------------------------------------------------
__device__ __forceinline__ float grad_elem(float om, float bw, const float* __restrict__ sp) {
  // omega_index = clip(floor(om/bw + 0.5), 0, 1000)   (IEEE fp32 div, like jnp)
  float q = om / bw + 0.5f;
  int idx = (int)floorf(q);
  idx = min(max(idx, 0), 1000);
  float shift = om - ((float)idx + 0.5f) * bw;
  // pdf_pad = [p[0], p[0..999], p[998]]; left = pad[idx], right = pad[idx+1]
  float left  = sp[max(idx - 1, 0)];
  float right = sp[(idx == 1000) ? 998 : idx];
  float grad = (right - left) / bw;
  float accu = left + shift * grad;   // pdf_accurate (unnormalized; scale cancels)
  return grad / accu;
}

template <bool TRANS>
__global__ __launch_bounds__(TPB, 4) void igso3_main(
    const float* __restrict__ sigmas,
    const float* __restrict__ omegas,
    const float* __restrict__ omega_grid,
    const float* __restrict__ sine_src,  // TRANS ? [101][1024] transposed : [1000][101] original
    float* __restrict__ out,
    int B) {
  __shared__ float s_exp[L_TERMS * ROWS_PER_BLK];      // [l][r], r fastest (32B/row -> 2x b128 bcast)
  __shared__ float s_pdf[ROWS_PER_BLK][W_BINS];        // unnormalized series per row
  __shared__ float s_sig[ROWS_PER_BLK];

  const int tid = threadIdx.x;
  const int b0 = blockIdx.x * ROWS_PER_BLK;
  const int nr = min(ROWS_PER_BLK, B - b0);

  if (tid < ROWS_PER_BLK) s_sig[tid] = (tid < nr) ? sigmas[b0 + tid] : 1.0f;
  __syncthreads();

  // expon[l][r] = exp(-0.5*l*(l+1)*sigma_r^2)  (808 values, cooperative)
  for (int i = tid; i < L_TERMS * ROWS_PER_BLK; i += TPB) {
    int l = i >> 3;
    int r = i & 7;
    float s = s_sig[r];
    s_exp[i] = expf(-0.5f * (float)(l * (l + 1)) * s * s);
  }
  __syncthreads();

  // series[r][w] = sum_l expon[r][l] * sine_terms[w][l]
  // thread t owns w0 = 4t .. 4t+3 for all 8 rows -> 32 fp32 accumulators
  {
    float acc[ROWS_PER_BLK][4];
#pragma unroll
    for (int r = 0; r < ROWS_PER_BLK; ++r)
#pragma unroll
      for (int j = 0; j < 4; ++j) acc[r][j] = 0.0f;

    const int w0 = tid * 4;
    if (TRANS) {
#pragma unroll 2
      for (int l = 0; l < L_TERMS; ++l) {
        float4 sv = *(const float4*)(sine_src + (size_t)l * TRANS_STRIDE + w0);
        float4 e0 = *(const float4*)(s_exp + l * 8);
        float4 e1 = *(const float4*)(s_exp + l * 8 + 4);
        float es[8] = {e0.x, e0.y, e0.z, e0.w, e1.x, e1.y, e1.z, e1.w};
        float sva[4] = {sv.x, sv.y, sv.z, sv.w};
#pragma unroll
        for (int r = 0; r < ROWS_PER_BLK; ++r)
#pragma unroll
          for (int j = 0; j < 4; ++j)
            acc[r][j] = fmaf(es[r], sva[j], acc[r][j]);
      }
    } else if (w0 < W_BINS) {
      // fallback path (ws too small): strided reads of original layout
      for (int l = 0; l < L_TERMS; ++l) {
        float sva[4];
#pragma unroll
        for (int j = 0; j < 4; ++j) sva[j] = sine_src[(size_t)(w0 + j) * L_TERMS + l];
        float4 e0 = *(const float4*)(s_exp + l * 8);
        float4 e1 = *(const float4*)(s_exp + l * 8 + 4);
        float es[8] = {e0.x, e0.y, e0.z, e0.w, e1.x, e1.y, e1.z, e1.w};
#pragma unroll
        for (int r = 0; r < ROWS_PER_BLK; ++r)
#pragma unroll
          for (int j = 0; j < 4; ++j)
            acc[r][j] = fmaf(es[r], sva[j], acc[r][j]);
      }
    }

    if (w0 < W_BINS) {
#pragma unroll
      for (int r = 0; r < ROWS_PER_BLK; ++r) {
        float4 v = make_float4(acc[r][0], acc[r][1], acc[r][2], acc[r][3]);
        *(float4*)(&s_pdf[r][w0]) = v;  // 4000B row stride -> 16B aligned
      }
    }
  }
  __syncthreads();

  const float bw = omega_grid[1] - omega_grid[0];

  // streaming pass: 8 rows x 1024 float4 per block, coalesced
  const float4* __restrict__ om4 = (const float4*)(omegas + (size_t)b0 * N_COLS);
  float4* __restrict__ out4 = (float4*)(out + (size_t)b0 * N_COLS);
  const int total = nr * (N_COLS / 4);
  for (int i = tid; i < total; i += TPB) {
    int r = i >> 10;            // wave-uniform (256 | 1024)
    float s = s_sig[r];
    float4 om = om4[i];
    float4 res;
    if (s <= 0.6f) {            // gaussian_gll = -omega / sigma^2
      float s2 = s * s;
      res.x = -om.x / s2;
      res.y = -om.y / s2;
      res.z = -om.z / s2;
      res.w = -om.w / s2;
    } else {
      const float* sp = s_pdf[r];
      res.x = grad_elem(om.x, bw, sp);
      res.y = grad_elem(om.y, bw, sp);
      res.z = grad_elem(om.z, bw, sp);
      res.w = grad_elem(om.w, bw, sp);
    }
    out4[i] = res;
  }
}

// ---------------------------------------------------------------------------
extern "C" void kernel_launch(void* const* d_in, const int* in_sizes, int n_in,
                              void* d_out, int out_size, void* d_ws, size_t ws_size,
                              hipStream_t stream) {
  const float* sigmas     = (const float*)d_in[0];
  const float* omegas     = (const float*)d_in[1];
  const float* omega_grid = (const float*)d_in[2];
  // d_in[3] = ls (unused)
  const float* sine_terms = (const float*)d_in[4];
  float* out = (float*)d_out;

  const int B = in_sizes[0];  // 8192
  const int blocks = (B + ROWS_PER_BLK - 1) / ROWS_PER_BLK;

  const size_t need = (size_t)L_TERMS * TRANS_STRIDE * sizeof(float);  // 404 KB
  if (ws_size >= need) {
    transpose_sine<<<W_BINS, 128, 0, stream>>>(sine_terms, (float*)d_ws);
    igso3_main<true><<<blocks, TPB, 0, stream>>>(sigmas, omegas, omega_grid,
                                                 (const float*)d_ws, out, B);
  } else {
    igso3_main<false><<<blocks, TPB, 0, stream>>>(sigmas, omegas, omega_grid,
                                                  sine_terms, out, B);
  }
}

// Round 2
// 257.183 us; speedup vs baseline: 1.1548x; 1.1548x over previous
//
#include <hip/hip_runtime.h>
#include <hip/hip_bf16.h>

// Problem constants (fixed by the reference):
//   B=8192 rows, N=4096 omegas/row, W=1000 bins, L=101 Legendre terms.
// Exact simplifications:
//   * pdf normalization cancels in grad/pdf -> skipped
//   * gauss branch of _pdf_no_cosine never selected when pdf is used
//     (needs sigma>0.6>0.2) -> skipped
//   * sigma<=0.6 rows are pure elementwise -omega/sigma^2 (pdf unused)
//   * series terms with 0.5*l*(l+1)*sigma^2 > ~44 underflow vs pdf scale
//     (sigma>0.6 -> l_max <= ~15); truncation error < 1e-15 abs.

#define L_TERMS 101
#define W_BINS 1000
#define N_COLS 4096
#define ROWS_PER_BLK 4
#define TPB 256
#define TRANS_STRIDE 1024   // padded transpose row stride
#define PAD_W 1002          // padded pdf table: tab[k] = p[k-1], k=1..1000
#define GRAD_T 0.6f

__device__ __forceinline__ float fast_rcp(float x) {
  return __builtin_amdgcn_rcpf(x);
}

// ---------------------------------------------------------------------------
// Kernel 1: transpose sine_terms [1000][101] -> sine_t [101][1024] (padded)
__global__ __launch_bounds__(128) void transpose_sine(
    const float* __restrict__ sine, float* __restrict__ sine_t) {
  int w = blockIdx.x;   // 0..999
  int t = threadIdx.x;  // 0..127
  if (t < L_TERMS) sine_t[(size_t)t * TRANS_STRIDE + w] = sine[(size_t)w * L_TERMS + t];
}

// ---------------------------------------------------------------------------
template <bool TRANS>
__global__ __launch_bounds__(TPB, 8) void igso3_main(
    const float* __restrict__ sigmas,
    const float* __restrict__ omegas,
    const float* __restrict__ omega_grid,
    const float* __restrict__ sine_src,  // TRANS ? [101][1024] : [1000][101]
    float* __restrict__ out,
    int B) {
  __shared__ float s_exp[L_TERMS * ROWS_PER_BLK];   // [l][r], r fastest
  __shared__ float s_pdf[ROWS_PER_BLK][PAD_W];      // padded unnormalized series
  __shared__ float s_sig[ROWS_PER_BLK];

  const int tid = threadIdx.x;
  const int b0 = blockIdx.x * ROWS_PER_BLK;
  const int nr = min(ROWS_PER_BLK, B - b0);

  if (tid < ROWS_PER_BLK) s_sig[tid] = (tid < nr) ? sigmas[b0 + tid] : 1.0f;
  __syncthreads();

  // Per-block truncation depth over rows that actually use the series.
  int lmax = 0;
#pragma unroll
  for (int r = 0; r < ROWS_PER_BLK; ++r) {
    float s = s_sig[r];
    if (r < nr && s > GRAD_T) {
      // smallest l with 0.5*l*(l+1)*s^2 >= 44  ->  l(l+1) >= 88/s^2
      float le = ceilf((-1.0f + sqrtf(1.0f + 352.0f / (s * s))) * 0.5f) + 1.0f;
      int li = (int)le;
      lmax = max(lmax, min(max(li, 1), L_TERMS));
    }
  }

  if (lmax > 0) {
    // expon[l][r] = exp(-0.5*l*(l+1)*sigma_r^2), only l < lmax needed
    for (int i = tid; i < lmax * ROWS_PER_BLK; i += TPB) {
      int l = i >> 2;
      int r = i & 3;
      float s = s_sig[r];
      s_exp[i] = __expf(-0.5f * (float)(l * (l + 1)) * s * s);
    }
    __syncthreads();

    // series[r][w] = sum_l expon[r][l] * sine_terms[w][l]
    float acc[ROWS_PER_BLK][4];
#pragma unroll
    for (int r = 0; r < ROWS_PER_BLK; ++r)
#pragma unroll
      for (int j = 0; j < 4; ++j) acc[r][j] = 0.0f;

    const int w0 = tid * 4;
    if (TRANS) {
      for (int l = 0; l < lmax; ++l) {
        float4 sv = *(const float4*)(sine_src + (size_t)l * TRANS_STRIDE + w0);
        float4 ev = *(const float4*)(s_exp + l * 4);  // broadcast b128
        float es[4] = {ev.x, ev.y, ev.z, ev.w};
        float sva[4] = {sv.x, sv.y, sv.z, sv.w};
#pragma unroll
        for (int r = 0; r < ROWS_PER_BLK; ++r)
#pragma unroll
          for (int j = 0; j < 4; ++j)
            acc[r][j] = fmaf(es[r], sva[j], acc[r][j]);
      }
    } else if (w0 < W_BINS) {
      for (int l = 0; l < lmax; ++l) {
        float sva[4];
#pragma unroll
        for (int j = 0; j < 4; ++j) sva[j] = sine_src[(size_t)(w0 + j) * L_TERMS + l];
        float4 ev = *(const float4*)(s_exp + l * 4);
        float es[4] = {ev.x, ev.y, ev.z, ev.w};
#pragma unroll
        for (int r = 0; r < ROWS_PER_BLK; ++r)
#pragma unroll
          for (int j = 0; j < 4; ++j)
            acc[r][j] = fmaf(es[r], sva[j], acc[r][j]);
      }
    }

    if (w0 < W_BINS) {
#pragma unroll
      for (int r = 0; r < ROWS_PER_BLK; ++r)
#pragma unroll
        for (int j = 0; j < 4; ++j)
          s_pdf[r][w0 + 1 + j] = acc[r][j];   // tab[k]=p[k-1]
    }
    if (tid < ROWS_PER_BLK) {
      // pads: tab[0]=p[0], tab[1001]=p[998]
      // (safe: written after the barrier below? no — same phase; guard with sync)
    }
  }
  __syncthreads();
  if (lmax > 0 && tid < ROWS_PER_BLK) {
    s_pdf[tid][0] = s_pdf[tid][1];
    s_pdf[tid][1001] = s_pdf[tid][999];
  }
  __syncthreads();

  const float bw = omega_grid[1] - omega_grid[0];
  const float inv_bw = 1.0f / bw;

  // streaming pass: coalesced float4, row wave-uniform (i>>10)
  const float4* __restrict__ om4 = (const float4*)(omegas + (size_t)b0 * N_COLS);
  float4* __restrict__ out4 = (float4*)(out + (size_t)b0 * N_COLS);
  const int total = nr * (N_COLS / 4);
#pragma unroll 2
  for (int i = tid; i < total; i += TPB) {
    int r = i >> 10;            // N_COLS/4 = 1024 float4 per row
    float s = s_sig[r];
    float4 om = om4[i];
    float4 res;
    if (s <= GRAD_T) {          // gaussian_gll = -omega / sigma^2
      float inv_s2 = fast_rcp(s * s);
      res.x = -om.x * inv_s2;
      res.y = -om.y * inv_s2;
      res.z = -om.z * inv_s2;
      res.w = -om.w * inv_s2;
    } else {
      const float* tab = s_pdf[r];
      float omv[4] = {om.x, om.y, om.z, om.w};
      float rv[4];
#pragma unroll
      for (int j = 0; j < 4; ++j) {
        float o = omv[j];
        int idx = (int)floorf(fmaf(o, inv_bw, 0.5f));
        idx = min(max(idx, 0), 1000);
        float shift = fmaf(-((float)idx + 0.5f), bw, o);
        const float* base = tab + idx;
        float left = base[0];    // ds_read2_b32
        float right = base[1];
        float grad = (right - left) * inv_bw;
        float accu = fmaf(shift, grad, left);
        rv[j] = grad * fast_rcp(accu);
      }
      res.x = rv[0]; res.y = rv[1]; res.z = rv[2]; res.w = rv[3];
    }
    out4[i] = res;
  }
}

// ---------------------------------------------------------------------------
extern "C" void kernel_launch(void* const* d_in, const int* in_sizes, int n_in,
                              void* d_out, int out_size, void* d_ws, size_t ws_size,
                              hipStream_t stream) {
  const float* sigmas     = (const float*)d_in[0];
  const float* omegas     = (const float*)d_in[1];
  const float* omega_grid = (const float*)d_in[2];
  // d_in[3] = ls (unused)
  const float* sine_terms = (const float*)d_in[4];
  float* out = (float*)d_out;

  const int B = in_sizes[0];  // 8192
  const int blocks = (B + ROWS_PER_BLK - 1) / ROWS_PER_BLK;

  const size_t need = (size_t)L_TERMS * TRANS_STRIDE * sizeof(float);  // ~404 KB
  if (ws_size >= need) {
    transpose_sine<<<W_BINS, 128, 0, stream>>>(sine_terms, (float*)d_ws);
    igso3_main<true><<<blocks, TPB, 0, stream>>>(sigmas, omegas, omega_grid,
                                                 (const float*)d_ws, out, B);
  } else {
    igso3_main<false><<<blocks, TPB, 0, stream>>>(sigmas, omegas, omega_grid,
                                                  sine_terms, out, B);
  }
}

// Round 3
// 248.296 us; speedup vs baseline: 1.1961x; 1.0358x over previous
//
#include <hip/hip_runtime.h>
#include <hip/hip_bf16.h>

// B=8192 rows, N=4096 omegas/row, W=1000 bins, L=101 Legendre terms.
// Exact simplifications:
//   * pdf normalization cancels in grad/pdf -> skipped
//   * gauss branch of _pdf_no_cosine never selected when pdf is used
//     (needs sigma>0.6>0.2) -> skipped
//   * sigma<=0.6 rows are pure elementwise -omega/sigma^2 (pdf unused)
//   * series terms with 0.5*l*(l+1)*sigma^2 > 44 underflow vs pdf scale
//     (sigma>0.6 -> lmax <= 17); truncation error < 1e-14 abs.
// Structure: 1 row per block (grid=8192 -> 4 residency waves/CU so the
// latency-chained table build of later blocks overlaps streaming of earlier
// ones). LDS ~4.2 KB. Nontemporal stores keep omegas resident in LLC.

#define L_TERMS 101
#define W_BINS 1000
#define N_COLS 4096
#define TPB 256
#define TRANS_STRIDE 1024   // padded transpose row stride (w0+3 <= 1023 in-bounds)
#define PAD_W 1004          // shifted pdf table: tab[k] = p[k-1], k=1..1000
#define GRAD_T 0.6f
#define LMAX_CAP 32         // formula gives <=17 for sigma>0.6

typedef float v4f __attribute__((ext_vector_type(4)));

// ---------------------------------------------------------------------------
// Kernel 1: transpose sine_terms [1000][101] -> sine_t [101][1024] (padded)
__global__ __launch_bounds__(128) void transpose_sine(
    const float* __restrict__ sine, float* __restrict__ sine_t) {
  int w = blockIdx.x;   // 0..999
  int t = threadIdx.x;  // 0..127
  if (t < L_TERMS) sine_t[(size_t)t * TRANS_STRIDE + w] = sine[(size_t)w * L_TERMS + t];
}

// ---------------------------------------------------------------------------
template <bool TRANS>
__global__ __launch_bounds__(TPB, 8) void igso3_main(
    const float* __restrict__ sigmas,
    const float* __restrict__ omegas,
    const float* __restrict__ omega_grid,
    const float* __restrict__ sine_src,  // TRANS ? [101][1024] : [1000][101]
    float* __restrict__ out) {
  __shared__ float s_exp[LMAX_CAP];
  __shared__ float s_pdf[PAD_W];   // tab[k] = p[k-1]; tab[0]=p[0], tab[1001]=p[998]

  const int tid = threadIdx.x;
  const int b = blockIdx.x;
  const float s = sigmas[b];       // uniform -> scalar load

  const float bw = omega_grid[1] - omega_grid[0];
  const float inv_bw = 1.0f / bw;  // IEEE, computed once

  const v4f* __restrict__ om4 = (const v4f*)(omegas + (size_t)b * N_COLS);
  v4f* __restrict__ out4 = (v4f*)(out + (size_t)b * N_COLS);

  if (s <= GRAD_T) {
    // pure elementwise row: -omega / sigma^2
    const float inv_s2 = __builtin_amdgcn_rcpf(s * s);
    v4f om[4];
#pragma unroll
    for (int k = 0; k < 4; ++k) om[k] = om4[k * TPB + tid];
#pragma unroll
    for (int k = 0; k < 4; ++k) {
      v4f r = om[k] * (-inv_s2);
      __builtin_nontemporal_store(r, &out4[k * TPB + tid]);
    }
    return;   // block-uniform: no barrier ever executed in this block
  }

  // ---- table build (block-uniform path) ----
  // smallest l with 0.5*l*(l+1)*s^2 >= 44  ->  l >= (-1+sqrt(1+352/s^2))/2
  float le = ceilf((-1.0f + sqrtf(1.0f + 352.0f / (s * s))) * 0.5f) + 1.0f;
  int lmax = min((int)le, LMAX_CAP);

  if (tid < lmax) s_exp[tid] = __expf(-0.5f * (float)(tid * (tid + 1)) * s * s);
  __syncthreads();

  const int w0 = tid * 4;
  float acc[4] = {0.0f, 0.0f, 0.0f, 0.0f};
  if (TRANS) {
    for (int l = 0; l < lmax; ++l) {
      v4f sv = *(const v4f*)(sine_src + (size_t)l * TRANS_STRIDE + w0);
      float e = s_exp[l];   // same-address LDS broadcast
      acc[0] = fmaf(e, sv.x, acc[0]);
      acc[1] = fmaf(e, sv.y, acc[1]);
      acc[2] = fmaf(e, sv.z, acc[2]);
      acc[3] = fmaf(e, sv.w, acc[3]);
    }
  } else if (w0 < W_BINS) {
    for (int l = 0; l < lmax; ++l) {
      float e = s_exp[l];
#pragma unroll
      for (int j = 0; j < 4; ++j)
        acc[j] = fmaf(e, sine_src[(size_t)(w0 + j) * L_TERMS + l], acc[j]);
    }
  }
  if (w0 < W_BINS) {
#pragma unroll
    for (int j = 0; j < 4; ++j) s_pdf[w0 + 1 + j] = acc[j];
    if (tid == 0) s_pdf[0] = acc[0];          // pad left  = p[0]
    if (w0 == 996) s_pdf[1001] = acc[2];      // pad right = p[998]
  }
  __syncthreads();

  // ---- streaming gather: 4 float4 per thread, loads hoisted ----
  v4f om[4];
#pragma unroll
  for (int k = 0; k < 4; ++k) om[k] = om4[k * TPB + tid];
#pragma unroll
  for (int k = 0; k < 4; ++k) {
    float o[4] = {om[k].x, om[k].y, om[k].z, om[k].w};
    float rv[4];
#pragma unroll
    for (int j = 0; j < 4; ++j) {
      // omega >= 0 -> q >= 0.5 -> int-cast == floor; idx >= 0 guaranteed
      int idx = (int)fmaf(o[j], inv_bw, 0.5f);
      idx = min(idx, 1000);
      float shift = fmaf(-((float)idx + 0.5f), bw, o[j]);
      float left  = s_pdf[idx];        // ds_read2_b32 pair
      float right = s_pdf[idx + 1];
      float grad = (right - left) * inv_bw;
      float accu = fmaf(shift, grad, left);
      rv[j] = grad * __builtin_amdgcn_rcpf(accu);
    }
    v4f res = {rv[0], rv[1], rv[2], rv[3]};
    __builtin_nontemporal_store(res, &out4[k * TPB + tid]);
  }
}

// ---------------------------------------------------------------------------
extern "C" void kernel_launch(void* const* d_in, const int* in_sizes, int n_in,
                              void* d_out, int out_size, void* d_ws, size_t ws_size,
                              hipStream_t stream) {
  const float* sigmas     = (const float*)d_in[0];
  const float* omegas     = (const float*)d_in[1];
  const float* omega_grid = (const float*)d_in[2];
  // d_in[3] = ls (unused)
  const float* sine_terms = (const float*)d_in[4];
  float* out = (float*)d_out;

  const int B = in_sizes[0];  // 8192 -> one block per row

  const size_t need = (size_t)L_TERMS * TRANS_STRIDE * sizeof(float);  // ~404 KB
  if (ws_size >= need) {
    transpose_sine<<<W_BINS, 128, 0, stream>>>(sine_terms, (float*)d_ws);
    igso3_main<true><<<B, TPB, 0, stream>>>(sigmas, omegas, omega_grid,
                                            (const float*)d_ws, out);
  } else {
    igso3_main<false><<<B, TPB, 0, stream>>>(sigmas, omegas, omega_grid,
                                             sine_terms, out);
  }
}